// Round 7
// baseline (150.877 us; speedup 1.0000x reference)
//
#include <hip/hip_runtime.h>
#include <hip/hip_bf16.h>
#include <stdint.h>

// GAT: B=4, N=2048, F_IN=F_OUT=256, H=4
#define H 4
#define BB 4
#define NN 2048
#define FIN 256
#define FOUT 256
#define M_TOT (BB*NN)   // 8192
#define LOG2E 1.44269504f

typedef float f32x4 __attribute__((ext_vector_type(4)));
typedef short s16x8 __attribute__((ext_vector_type(8)));
typedef unsigned int u32;

static __device__ __forceinline__ short f2bf(float f) {
    return __builtin_bit_cast(short, __float2bfloat16(f));
}
static __device__ __forceinline__ float bf2f(short u) {
    unsigned x = ((unsigned)(unsigned short)u) << 16;
    return __builtin_bit_cast(float, x);
}
// async global->LDS, 16B per lane (dest = wave-uniform base + lane*16)
static __device__ __forceinline__ void glds16(const void* g, void* l) {
    __builtin_amdgcn_global_load_lds(
        (const __attribute__((address_space(1))) u32*)(g),
        (__attribute__((address_space(3))) u32*)(l), 16, 0, 0);
}

// ---------------- prep: W[h][k][o] -> WT[h][o][k] (bf16) ----------------
__global__ __launch_bounds__(256) void k_wt(const float* __restrict__ W, short* __restrict__ WT) {
    __shared__ float lds[64][65];
    int bid = blockIdx.x;
    int h = bid >> 4, kt = (bid >> 2) & 3, ot = bid & 3;
    int kb = kt * 64, ob = ot * 64;
    int tx = threadIdx.x & 63, ty = threadIdx.x >> 6;
#pragma unroll
    for (int r = 0; r < 16; ++r) {
        int k_l = ty + r * 4;
        lds[tx][k_l] = W[(size_t)(h * FIN + kb + k_l) * FOUT + ob + tx];
    }
    __syncthreads();
#pragma unroll
    for (int r = 0; r < 16; ++r) {
        int o_l = ty + r * 4;
        WT[(size_t)(h * FOUT + ob + o_l) * FIN + kb + tx] = f2bf(lds[o_l][tx]);
    }
}

// ---------------- prep: q[h][f] = sum_o W[h][f][o]*a[h][o] ----------------
__global__ __launch_bounds__(256) void k_q(const float* __restrict__ W, const float* __restrict__ a,
                                           float* __restrict__ q) {
    int wv = (blockIdx.x * 256 + threadIdx.x) >> 6;  // 0..1023
    int lane = threadIdx.x & 63;
    int h = wv >> 8, f = wv & 255;
    float4 w4 = *(const float4*)(W + (size_t)(h * FIN + f) * FOUT + lane * 4);
    float4 a4 = *(const float4*)(a + h * FOUT + lane * 4);
    float d = w4.x * a4.x + w4.y * a4.y + w4.z * a4.z + w4.w * a4.w;
#pragma unroll
    for (int off = 32; off; off >>= 1) d += __shfl_xor(d, off);
    if (lane == 0) q[h * FIN + f] = d;
}

// ---------------- prep: c[h] = b[h] . a[h] ----------------
__global__ __launch_bounds__(256) void k_c(const float* __restrict__ bvec, const float* __restrict__ a,
                                           float* __restrict__ c) {
    int h = threadIdx.x >> 6, lane = threadIdx.x & 63;
    float4 b4 = *(const float4*)(bvec + h * FOUT + lane * 4);
    float4 a4 = *(const float4*)(a + h * FOUT + lane * 4);
    float d = b4.x * a4.x + b4.y * a4.y + b4.z * a4.z + b4.w * a4.w;
#pragma unroll
    for (int off = 32; off; off >>= 1) d += __shfl_xor(d, off);
    if (lane == 0) c[h] = d;
}

// ---------------- scores (exact fp32) + X->bf16 conversion (fused) ----------------
__global__ __launch_bounds__(256) void k_s(const float* __restrict__ X, const float* __restrict__ q,
                                           const float* __restrict__ c, float* __restrict__ s,
                                           short* __restrict__ Xbf) {
    int m = blockIdx.x * 4 + (threadIdx.x >> 6);
    int lane = threadIdx.x & 63;
    float4 xv = *(const float4*)(X + (size_t)m * FIN + lane * 4);
    short4 xb;
    xb.x = f2bf(xv.x); xb.y = f2bf(xv.y); xb.z = f2bf(xv.z); xb.w = f2bf(xv.w);
    *(short4*)(Xbf + (size_t)m * FIN + lane * 4) = xb;
#pragma unroll
    for (int h = 0; h < H; ++h) {
        float4 qv = *(const float4*)(q + h * FIN + lane * 4);
        float d = xv.x * qv.x + xv.y * qv.y + xv.z * qv.z + xv.w * qv.w;
#pragma unroll
        for (int off = 32; off; off >>= 1) d += __shfl_xor(d, off);
        if (lane == 0) s[h * M_TOT + m] = d + c[h];
    }
}

// ---------------- bias -> edge mask bits + per-row masked max of s_j ----------------
__global__ __launch_bounds__(256) void k_maskmax(const float* __restrict__ bias, const float* __restrict__ s,
                                                 unsigned* __restrict__ mask, float* __restrict__ mx) {
    int w = threadIdx.x >> 6, lane = threadIdx.x & 63;
    int row = blockIdx.x * 4 + w;          // 0..8191 = b*N + i
    const float* bp = bias + (size_t)row * NN + lane * 32;
    unsigned bits = 0;
#pragma unroll
    for (int k = 0; k < 8; ++k) {
        float4 v = *(const float4*)(bp + k * 4);
        bits |= (v.x > -1.f ? 1u : 0u) << (k * 4 + 0);
        bits |= (v.y > -1.f ? 1u : 0u) << (k * 4 + 1);
        bits |= (v.z > -1.f ? 1u : 0u) << (k * 4 + 2);
        bits |= (v.w > -1.f ? 1u : 0u) << (k * 4 + 3);
    }
    mask[(size_t)row * 64 + lane] = bits;
    int b = row >> 11;
#pragma unroll
    for (int h = 0; h < H; ++h) {
        const float* sp = s + h * M_TOT + b * NN + lane * 32;
        float m = -3e38f;
#pragma unroll
        for (int k = 0; k < 8; ++k) {
            float4 sv = *(const float4*)(sp + k * 4);
            m = fmaxf(m, ((bits >> (k * 4 + 0)) & 1u) ? sv.x : -3e38f);
            m = fmaxf(m, ((bits >> (k * 4 + 1)) & 1u) ? sv.y : -3e38f);
            m = fmaxf(m, ((bits >> (k * 4 + 2)) & 1u) ? sv.z : -3e38f);
            m = fmaxf(m, ((bits >> (k * 4 + 3)) & 1u) ? sv.w : -3e38f);
        }
#pragma unroll
        for (int off = 32; off; off >>= 1) m = fmaxf(m, __shfl_xor(m, off));
        if (lane == 0) mx[h * M_TOT + row] = m;
    }
}

// ---------------- tTs = bf16(X@W + b), written as swizzled LDS-image (coalesced) ----------------
// image: per (h,b): 32 j-tiles of 32KB; tile = [o:256][8 chunks of 8 shorts],
// chunk_phys = ((j>>3)&7) ^ (o&7).
__global__ __launch_bounds__(256) void k_gemm_t(const short* __restrict__ WT, const short* __restrict__ Xbf,
                                                const float* __restrict__ bvec, short* __restrict__ tTs) {
    __shared__ short ot[64][136];   // bf16 D-tile [64 o][128 m], pad 8
    int h = blockIdx.z;
    int ob = blockIdx.y * 64;
    int mb = blockIdx.x * 128;
    int tid = threadIdx.x;
    int lane = tid & 63, w = tid >> 6;
    int r16 = lane & 15, g = lane >> 4;
    int mw = mb + w * 32;
    f32x4 acc[4][2] = {};
    for (int k = 0; k < FIN; k += 32) {
        s16x8 afr[4], bfr[2];
#pragma unroll
        for (int fa = 0; fa < 4; ++fa)
            afr[fa] = *(const s16x8*)(WT + (size_t)(h * FOUT + ob + fa * 16 + r16) * FIN + k + g * 8);
#pragma unroll
        for (int fb = 0; fb < 2; ++fb)
            bfr[fb] = *(const s16x8*)(Xbf + (size_t)(mw + fb * 16 + r16) * FIN + k + g * 8);
#pragma unroll
        for (int fa = 0; fa < 4; ++fa)
#pragma unroll
            for (int fb = 0; fb < 2; ++fb)
                acc[fa][fb] = __builtin_amdgcn_mfma_f32_16x16x32_bf16(afr[fa], bfr[fb], acc[fa][fb], 0, 0, 0);
    }
    // acc -> LDS (bf16)
#pragma unroll
    for (int fa = 0; fa < 4; ++fa) {
#pragma unroll
        for (int r = 0; r < 4; ++r) {
            int o_l = fa * 16 + g * 4 + r;
            float bv = bvec[h * FOUT + ob + o_l];
#pragma unroll
            for (int fb = 0; fb < 2; ++fb)
                ot[o_l][w * 32 + fb * 16 + r16] = f2bf(acc[fa][fb][r] + bv);
        }
    }
    __syncthreads();
    // coalesced 16B image stores: thread -> (o_l base, m-group)
    int ol0 = tid >> 4;        // 0..15
    int mg  = tid & 15;        // 0..15
    int j0  = mb + mg * 8;     // global m (block is within one b)
    int bb  = j0 >> 11;
    int j   = j0 & 2047;
#pragma unroll
    for (int cc = 0; cc < 4; ++cc) {
        int o_l = ol0 + cc * 16;
        int o = ob + o_l;
        s16x8 v = *(const s16x8*)&ot[o_l][mg * 8];
        size_t addr = ((size_t)((h * 4 + bb) * 32 + (j >> 6))) * 16384
                    + o * 64 + ((((j >> 3) & 7) ^ (o & 7)) << 3);
        *(s16x8*)(tTs + addr) = v;
    }
}

// ---------------- streaming softmax-PV: OT[h][o][m] (bf16) ----------------
// 512 threads = 8 waves: oh=w&1 (o-half 128), par=(w>>1)&1 (j-half 32), qg=w>>2 (2 q-groups).
// q-block 64, grid 512 = 2 blocks/CU (64KB LDS double-buffer) -> 16 waves/CU.
// A-traffic per block halved vs Sq=4. Precomputed row max; l via ones-row MFMA.
__global__ __launch_bounds__(512, 4) void k_attn(const short* __restrict__ tTs, const float* __restrict__ s,
                                                 const unsigned* __restrict__ mask, const float* __restrict__ mx,
                                                 short* __restrict__ OT) {
    extern __shared__ short smem[];   // 2 x 16384 shorts = 65536 B

    // T1: bijective XCD swizzle (512 blocks)
    int flat = blockIdx.x + 32 * (blockIdx.y + 4 * blockIdx.z);
    int swz = (flat & 7) * 64 + (flat >> 3);
    int qt = swz & 31, b = (swz >> 5) & 3, h = swz >> 7;
    int ib = qt * 64;

    int tid = threadIdx.x;
    int lane = tid & 63, w = tid >> 6;
    int r16 = lane & 15, g = lane >> 4;
    int oh = w & 1, par = (w >> 1) & 1, qg = w >> 2;
    int i0 = ib + qg * 32 + r16, i1 = i0 + 16;
    size_t gm = (size_t)b * NN;

    const char* slab = (const char*)(tTs + (size_t)(h * 4 + b) * 32 * 16384);
    const float* srow = s + h * M_TOT + gm;
    float si0 = srow[i0], si1 = srow[i1];
    float mx0 = mx[h * M_TOT + gm + i0];
    float mx1 = mx[h * M_TOT + gm + i1];
    float z0 = si0 + mx0, z1 = si1 + mx1;
    float Mlog0 = fmaxf(z0, 0.2f * z0) * LOG2E;
    float Mlog1 = fmaxf(z1, 0.2f * z1) * LOG2E;
    float siL0 = si0 * LOG2E, siL1 = si1 * LOG2E;
    const unsigned* mk0 = mask + (gm + i0) * 64;
    const unsigned* mk1 = mask + (gm + i1) * 64;

    // LDS read offset (shorts): o = oh*128 + f*16 + r16, chunk (par*4+g)^(o&7)
    int rd_base = oh * 8192 + r16 * 64 + ((((par << 2) + g) ^ (r16 & 7)) << 3);

    f32x4 acc[8][2] = {};
    f32x4 accl[2] = {};
    s16x8 ones;
#pragma unroll
    for (int e = 0; e < 8; ++e) ones[e] = (short)0x3F80;  // bf16 1.0

    auto stage = [&](int tt, int slot) {
        const char* gs = slab + (size_t)tt * 32768 + w * 1024 + (size_t)lane * 16;
        short* ldb = smem + slot * 16384 + w * 512;
        glds16(gs,          ldb);
        glds16(gs +  8192,  ldb + 4096);
        glds16(gs + 16384,  ldb + 8192);
        glds16(gs + 24576,  ldb + 12288);
    };
    float4 psj0, psj1; unsigned pw0, pw1;
    auto preload = [&](int tt) {
        int jw = tt * 64 + par * 32;
        psj0 = *(const float4*)(srow + jw + g * 8);
        psj1 = *(const float4*)(srow + jw + g * 8 + 4);
        pw0 = mk0[tt * 2 + par];
        pw1 = mk1[tt * 2 + par];
    };

    stage(0, 0);
    preload(0);
    asm volatile("s_waitcnt vmcnt(0)" ::: "memory");
    __builtin_amdgcn_s_barrier();
    __builtin_amdgcn_sched_barrier(0);

    for (int t = 0; t < 32; ++t) {
        int cur = t & 1;
        if (t < 31) stage(t + 1, cur ^ 1);

        // ---- scores from preloaded regs (pure VALU, no cross-lane) ----
        float sjv[8] = {psj0.x, psj0.y, psj0.z, psj0.w, psj1.x, psj1.y, psj1.z, psj1.w};
        unsigned b0 = pw0 >> (g * 8), b1 = pw1 >> (g * 8);
        s16x8 pb0, pb1;
#pragma unroll
        for (int e = 0; e < 8; ++e) {
            float yL0 = fmaf(sjv[e], LOG2E, siL0);
            float yL1 = fmaf(sjv[e], LOG2E, siL1);
            float ly0 = fmaxf(yL0, 0.2f * yL0);
            float ly1 = fmaxf(yL1, 0.2f * yL1);
            float a0 = ((b0 >> e) & 1u) ? (ly0 - Mlog0) : -200.f;  // <= 0 always
            float a1 = ((b1 >> e) & 1u) ? (ly1 - Mlog1) : -200.f;
            pb0[e] = f2bf(__builtin_amdgcn_exp2f(a0));
            pb1[e] = f2bf(__builtin_amdgcn_exp2f(a1));
        }

        __builtin_amdgcn_sched_barrier(0);
        asm volatile("s_waitcnt vmcnt(4)" ::: "memory");   // buf[cur] drained (4 = stage(t+1))
        __builtin_amdgcn_s_barrier();
        __builtin_amdgcn_sched_barrier(0);

        // ---- PV MFMAs: 8 A-frags (o-half) x 2 q-frags + ones-row (l) ----
        const short* bt = smem + cur * 16384;
        __builtin_amdgcn_s_setprio(1);
#pragma unroll
        for (int f = 0; f < 8; ++f) {
            s16x8 af = *(const s16x8*)(bt + f * 1024 + rd_base);
            acc[f][0] = __builtin_amdgcn_mfma_f32_16x16x32_bf16(af, pb0, acc[f][0], 0, 0, 0);
            acc[f][1] = __builtin_amdgcn_mfma_f32_16x16x32_bf16(af, pb1, acc[f][1], 0, 0, 0);
        }
        accl[0] = __builtin_amdgcn_mfma_f32_16x16x32_bf16(ones, pb0, accl[0], 0, 0, 0);
        accl[1] = __builtin_amdgcn_mfma_f32_16x16x32_bf16(ones, pb1, accl[1], 0, 0, 0);
        __builtin_amdgcn_s_setprio(0);

        if (t < 31) preload(t + 1);
        __builtin_amdgcn_sched_barrier(0);
        __builtin_amdgcn_s_barrier();   // all waves done reading buf[cur] before next stage overwrites
    }

    // ---- epilogue: par-pair partial-sum merge (plain add), store bf16 O^T ----
    __syncthreads();
    f32x4* ex = (f32x4*)smem;   // [pid:4][9][64] f32x4 = 36,864 B
    int pid = qg * 2 + oh;
#pragma unroll
    for (int qf = 0; qf < 2; ++qf) {
        if (par) {
#pragma unroll
            for (int f = 0; f < 8; ++f) ex[(pid * 9 + f) * 64 + lane] = acc[f][qf];
            ex[(pid * 9 + 8) * 64 + lane] = accl[qf];
        }
        __syncthreads();
        if (!par) {
            float lsum = accl[qf][0] + ex[(pid * 9 + 8) * 64 + lane][0];
            float inv = 1.f / lsum;
            int iq = qf ? i1 : i0;
            size_t base = (size_t)h * FOUT * M_TOT + gm + iq;
#pragma unroll
            for (int f = 0; f < 8; ++f) {
                f32x4 v = acc[f][qf] + ex[(pid * 9 + f) * 64 + lane];
#pragma unroll
                for (int rr = 0; rr < 4; ++rr) {
                    int o = oh * 128 + f * 16 + g * 4 + rr;
                    OT[base + (size_t)o * M_TOT] = f2bf(v[rr] * inv);
                }
            }
        }
        __syncthreads();
    }
}

// ---------------- head mean + transpose: out[m][o] = 0.25 * sum_h OT[h][o][m] ----------------
__global__ __launch_bounds__(256) void k_reduce(const short* __restrict__ OT, float* __restrict__ out) {
    __shared__ float lds[32][72];
    int mb = blockIdx.x * 64, obt = blockIdx.y * 32;
    int tid = threadIdx.x;
    {
        int o_l = tid >> 3;        // 0..31
        int m_l = (tid & 7) * 8;   // 0..56
        float acc[8] = {};
#pragma unroll
        for (int h = 0; h < H; ++h) {
            s16x8 v = *(const s16x8*)(OT + (size_t)(h * FOUT + obt + o_l) * M_TOT + mb + m_l);
#pragma unroll
            for (int e = 0; e < 8; ++e) acc[e] += bf2f(v[e]);
        }
#pragma unroll
        for (int e = 0; e < 8; ++e) lds[o_l][m_l + e] = acc[e] * 0.25f;
    }
    __syncthreads();
    {
        int m_l = tid >> 2;        // 0..63
        int o_l = (tid & 3) * 8;   // 0,8,16,24
        float4 v0, v1;
        v0.x = lds[o_l + 0][m_l]; v0.y = lds[o_l + 1][m_l];
        v0.z = lds[o_l + 2][m_l]; v0.w = lds[o_l + 3][m_l];
        v1.x = lds[o_l + 4][m_l]; v1.y = lds[o_l + 5][m_l];
        v1.z = lds[o_l + 6][m_l]; v1.w = lds[o_l + 7][m_l];
        float* dst = out + (size_t)(mb + m_l) * FOUT + obt + o_l;
        *(float4*)dst = v0;
        *(float4*)(dst + 4) = v1;
    }
}

extern "C" void kernel_launch(void* const* d_in, const int* in_sizes, int n_in,
                              void* d_out, int out_size, void* d_ws, size_t ws_size,
                              hipStream_t stream) {
    const float* X    = (const float*)d_in[0];  // [B,N,FIN]
    const float* bias = (const float*)d_in[1];  // [B,N,N]
    const float* W    = (const float*)d_in[2];  // [H,FIN,FOUT]
    const float* a    = (const float*)d_in[3];  // [H,FOUT]
    const float* bvec = (const float*)d_in[4];  // [H,FOUT]
    float* out = (float*)d_out;                 // [B,N,FOUT] f32

    // workspace layout (~40 MB high-water)
    char* ws = (char*)d_ws;
    short*    Xbf  = (short*)ws;                               //  4 MB  [8192][256] bf16
    short*    WT   = (short*)(ws + (4u << 20));                // 512 KB [H][256][256] bf16
    float*    q    = (float*)(ws + (4u << 20) + (768u << 10)); //  4 KB
    float*    c    = q + H * FIN;                              // 16 B
    float*    s    = (float*)(ws + (5u << 20));                // 128 KB [H][8192]
    float*    mxp  = (float*)(ws + (5u << 20) + (256u << 10)); // 128 KB [H][8192] row max
    short*    tTs  = (short*)(ws + (6u << 20));                // 16 MB  swizzled tile images
    short*    OT   = (short*)(ws + (22u << 20));               // 16 MB  [H][256][8192] bf16
    unsigned* mask = (unsigned*)(ws + (38u << 20));            //  2 MB  [B][N][N/32] bits

    k_wt<<<64, 256, 0, stream>>>(W, WT);
    k_q<<<256, 256, 0, stream>>>(W, a, q);
    k_c<<<1, 256, 0, stream>>>(bvec, a, c);
    k_s<<<2048, 256, 0, stream>>>(X, q, c, s, Xbf);
    k_maskmax<<<2048, 256, 0, stream>>>(bias, s, mask, mxp);
    k_gemm_t<<<dim3(64, 4, 4), 256, 0, stream>>>(WT, Xbf, bvec, tTs);
    k_attn<<<dim3(32, 4, 4), 512, 65536, stream>>>(tTs, s, mask, mxp, OT);
    k_reduce<<<dim3(128, 8), 256, 0, stream>>>(OT, out);
}

// Round 8
// 134.718 us; speedup vs baseline: 1.1199x; 1.1199x over previous
//
#include <hip/hip_runtime.h>
#include <hip/hip_bf16.h>
#include <stdint.h>

// GAT: B=4, N=2048, F_IN=F_OUT=256, H=4
#define H 4
#define BB 4
#define NN 2048
#define FIN 256
#define FOUT 256
#define M_TOT (BB*NN)   // 8192
#define LOG2E 1.44269504f

typedef float f32x4 __attribute__((ext_vector_type(4)));
typedef short s16x8 __attribute__((ext_vector_type(8)));
typedef unsigned int u32;

static __device__ __forceinline__ short f2bf(float f) {
    return __builtin_bit_cast(short, __float2bfloat16(f));
}
static __device__ __forceinline__ float bf2f(short u) {
    unsigned x = ((unsigned)(unsigned short)u) << 16;
    return __builtin_bit_cast(float, x);
}
// async global->LDS, 16B per lane (dest = wave-uniform base + lane*16)
static __device__ __forceinline__ void glds16(const void* g, void* l) {
    __builtin_amdgcn_global_load_lds(
        (const __attribute__((address_space(1))) u32*)(g),
        (__attribute__((address_space(3))) u32*)(l), 16, 0, 0);
}

// ---------------- prep (fused): W->WT (bf16), q = W.a, c = b.a ----------------
__global__ __launch_bounds__(256) void k_prep(const float* __restrict__ W, const float* __restrict__ a,
                                              const float* __restrict__ bvec,
                                              short* __restrict__ WT, float* __restrict__ q,
                                              float* __restrict__ c) {
    int bid = blockIdx.x;
    if (bid < 64) {
        __shared__ float lds[64][65];
        int h = bid >> 4, kt = (bid >> 2) & 3, ot = bid & 3;
        int kb = kt * 64, ob = ot * 64;
        int tx = threadIdx.x & 63, ty = threadIdx.x >> 6;
#pragma unroll
        for (int r = 0; r < 16; ++r) {
            int k_l = ty + r * 4;
            lds[tx][k_l] = W[(size_t)(h * FIN + kb + k_l) * FOUT + ob + tx];
        }
        __syncthreads();
#pragma unroll
        for (int r = 0; r < 16; ++r) {
            int o_l = ty + r * 4;
            WT[(size_t)(h * FOUT + ob + o_l) * FIN + kb + tx] = f2bf(lds[o_l][tx]);
        }
    } else if (bid < 320) {
        int wv = ((bid - 64) * 256 + threadIdx.x) >> 6;  // 0..1023
        int lane = threadIdx.x & 63;
        int h = wv >> 8, f = wv & 255;
        float4 w4 = *(const float4*)(W + (size_t)(h * FIN + f) * FOUT + lane * 4);
        float4 a4 = *(const float4*)(a + h * FOUT + lane * 4);
        float d = w4.x * a4.x + w4.y * a4.y + w4.z * a4.z + w4.w * a4.w;
#pragma unroll
        for (int off = 32; off; off >>= 1) d += __shfl_xor(d, off);
        if (lane == 0) q[h * FIN + f] = d;
    } else {
        int h = threadIdx.x >> 6, lane = threadIdx.x & 63;
        float4 b4 = *(const float4*)(bvec + h * FOUT + lane * 4);
        float4 a4 = *(const float4*)(a + h * FOUT + lane * 4);
        float d = b4.x * a4.x + b4.y * a4.y + b4.z * a4.z + b4.w * a4.w;
#pragma unroll
        for (int off = 32; off; off >>= 1) d += __shfl_xor(d, off);
        if (lane == 0) c[h] = d;
    }
}

// ---------------- scores (exact fp32) + X->bf16 conversion (fused) ----------------
__global__ __launch_bounds__(256) void k_s(const float* __restrict__ X, const float* __restrict__ q,
                                           const float* __restrict__ c, float* __restrict__ s,
                                           short* __restrict__ Xbf) {
    int m = blockIdx.x * 4 + (threadIdx.x >> 6);
    int lane = threadIdx.x & 63;
    float4 xv = *(const float4*)(X + (size_t)m * FIN + lane * 4);
    short4 xb;
    xb.x = f2bf(xv.x); xb.y = f2bf(xv.y); xb.z = f2bf(xv.z); xb.w = f2bf(xv.w);
    *(short4*)(Xbf + (size_t)m * FIN + lane * 4) = xb;
#pragma unroll
    for (int h = 0; h < H; ++h) {
        float4 qv = *(const float4*)(q + h * FIN + lane * 4);
        float d = xv.x * qv.x + xv.y * qv.y + xv.z * qv.z + xv.w * qv.w;
#pragma unroll
        for (int off = 32; off; off >>= 1) d += __shfl_xor(d, off);
        if (lane == 0) s[h * M_TOT + m] = d + c[h];
    }
}

// ---------------- bias -> edge mask bits + per-row masked max of s_j ----------------
__global__ __launch_bounds__(256) void k_maskmax(const float* __restrict__ bias, const float* __restrict__ s,
                                                 unsigned* __restrict__ mask, float* __restrict__ mx) {
    int w = threadIdx.x >> 6, lane = threadIdx.x & 63;
    int row = blockIdx.x * 4 + w;          // 0..8191 = b*N + i
    const float* bp = bias + (size_t)row * NN + lane * 32;
    unsigned bits = 0;
#pragma unroll
    for (int k = 0; k < 8; ++k) {
        float4 v = *(const float4*)(bp + k * 4);
        bits |= (v.x > -1.f ? 1u : 0u) << (k * 4 + 0);
        bits |= (v.y > -1.f ? 1u : 0u) << (k * 4 + 1);
        bits |= (v.z > -1.f ? 1u : 0u) << (k * 4 + 2);
        bits |= (v.w > -1.f ? 1u : 0u) << (k * 4 + 3);
    }
    mask[(size_t)row * 64 + lane] = bits;
    int b = row >> 11;
#pragma unroll
    for (int h = 0; h < H; ++h) {
        const float* sp = s + h * M_TOT + b * NN + lane * 32;
        float m = -3e38f;
#pragma unroll
        for (int k = 0; k < 8; ++k) {
            float4 sv = *(const float4*)(sp + k * 4);
            m = fmaxf(m, ((bits >> (k * 4 + 0)) & 1u) ? sv.x : -3e38f);
            m = fmaxf(m, ((bits >> (k * 4 + 1)) & 1u) ? sv.y : -3e38f);
            m = fmaxf(m, ((bits >> (k * 4 + 2)) & 1u) ? sv.z : -3e38f);
            m = fmaxf(m, ((bits >> (k * 4 + 3)) & 1u) ? sv.w : -3e38f);
        }
#pragma unroll
        for (int off = 32; off; off >>= 1) m = fmaxf(m, __shfl_xor(m, off));
        if (lane == 0) mx[h * M_TOT + row] = m;
    }
}

// ---------------- tTs = bf16(X@W + b), written as swizzled LDS-image (coalesced) ----------------
__global__ __launch_bounds__(256) void k_gemm_t(const short* __restrict__ WT, const short* __restrict__ Xbf,
                                                const float* __restrict__ bvec, short* __restrict__ tTs) {
    __shared__ short ot[64][136];   // bf16 D-tile [64 o][128 m], pad 8
    int h = blockIdx.z;
    int ob = blockIdx.y * 64;
    int mb = blockIdx.x * 128;
    int tid = threadIdx.x;
    int lane = tid & 63, w = tid >> 6;
    int r16 = lane & 15, g = lane >> 4;
    int mw = mb + w * 32;
    f32x4 acc[4][2] = {};
    for (int k = 0; k < FIN; k += 32) {
        s16x8 afr[4], bfr[2];
#pragma unroll
        for (int fa = 0; fa < 4; ++fa)
            afr[fa] = *(const s16x8*)(WT + (size_t)(h * FOUT + ob + fa * 16 + r16) * FIN + k + g * 8);
#pragma unroll
        for (int fb = 0; fb < 2; ++fb)
            bfr[fb] = *(const s16x8*)(Xbf + (size_t)(mw + fb * 16 + r16) * FIN + k + g * 8);
#pragma unroll
        for (int fa = 0; fa < 4; ++fa)
#pragma unroll
            for (int fb = 0; fb < 2; ++fb)
                acc[fa][fb] = __builtin_amdgcn_mfma_f32_16x16x32_bf16(afr[fa], bfr[fb], acc[fa][fb], 0, 0, 0);
    }
#pragma unroll
    for (int fa = 0; fa < 4; ++fa) {
#pragma unroll
        for (int r = 0; r < 4; ++r) {
            int o_l = fa * 16 + g * 4 + r;
            float bv = bvec[h * FOUT + ob + o_l];
#pragma unroll
            for (int fb = 0; fb < 2; ++fb)
                ot[o_l][w * 32 + fb * 16 + r16] = f2bf(acc[fa][fb][r] + bv);
        }
    }
    __syncthreads();
    int ol0 = tid >> 4;        // 0..15
    int mg  = tid & 15;        // 0..15
    int j0  = mb + mg * 8;
    int bb  = j0 >> 11;
    int j   = j0 & 2047;
#pragma unroll
    for (int cc = 0; cc < 4; ++cc) {
        int o_l = ol0 + cc * 16;
        int o = ob + o_l;
        s16x8 v = *(const s16x8*)&ot[o_l][mg * 8];
        size_t addr = ((size_t)((h * 4 + bb) * 32 + (j >> 6))) * 16384
                    + o * 64 + ((((j >> 3) & 7) ^ (o & 7)) << 3);
        *(s16x8*)(tTs + addr) = v;
    }
}

// ---------------- streaming softmax-PV with P-in-LDS: OT[h][o][m] (bf16) ----------------
// 512 threads = 8 waves: par=w&1 (j-half 32), oh=w>>1 (o-quarter 64). q-block 64.
// Each wave computes 1/8 of P (8 exp2/lane, NO redundancy) -> swizzled P_lds (8KB);
// after barrier reads 4 A-frags (1x redundancy) + 4 P-frags, 16 MFMA. l via ones-MFMA (oh==0).
// Double-buffered glds stage (64KB) + P (8KB) = 73.7KB -> 2 blocks/CU.
__global__ __launch_bounds__(512, 4) void k_attn(const short* __restrict__ tTs, const float* __restrict__ s,
                                                 const unsigned* __restrict__ mask, const float* __restrict__ mx,
                                                 short* __restrict__ OT) {
    extern __shared__ short smem[];      // 2*16384 stage + 4096 P = 36864 shorts
    short* Pl = smem + 32768;

    // T1: bijective XCD swizzle (512 blocks)
    int flat = blockIdx.x + 32 * (blockIdx.y + 4 * blockIdx.z);
    int swz = (flat & 7) * 64 + (flat >> 3);
    int qt = swz & 31, b = (swz >> 5) & 3, h = swz >> 7;
    int ib = qt * 64;

    int tid = threadIdx.x;
    int lane = tid & 63, w = tid >> 6;
    int r16 = lane & 15, g = lane >> 4;
    int par = w & 1, oh = w >> 1;        // oh 0..3
    size_t gm = (size_t)b * NN;

    const char* slab = (const char*)(tTs + (size_t)(h * 4 + b) * 32 * 16384);
    const float* srow = s + h * M_TOT + gm;

    // P-production row for this lane: i = ib + oh*16 + r16
    int i = ib + oh * 16 + r16;
    float si = srow[i];
    float mxi = mx[h * M_TOT + gm + i];
    float z = si + mxi;
    float Mlog = fmaxf(z, 0.2f * z) * LOG2E;
    float siL = si * LOG2E;
    const unsigned* mk = mask + (gm + i) * 64;

    // swizzled offsets (shorts); chunk = ((par*4+g) ^ (r16&7))*8
    int chk = ((((par << 2) + g) ^ (r16 & 7)) << 3);
    int rdA = (oh * 64 + r16) * 64 + chk;     // + f*1024
    int rdP = r16 * 64 + chk;                 // + qf*1024
    int wrP = oh * 1024 + rdP;                // write row oh*16+r16

    f32x4 acc[4][4] = {};
    f32x4 accl[4] = {};
    s16x8 ones;
#pragma unroll
    for (int e = 0; e < 8; ++e) ones[e] = (short)0x3F80;  // bf16 1.0

    // staging: wave w copies 4KB of the 32KB tile
    auto stage = [&](int tt, int slot) {
        const char* gs = slab + (size_t)tt * 32768 + w * 4096 + (size_t)lane * 16;
        short* ldb = smem + slot * 16384 + w * 2048;
        glds16(gs,         ldb);
        glds16(gs + 1024,  ldb + 512);
        glds16(gs + 2048,  ldb + 1024);
        glds16(gs + 3072,  ldb + 1536);
    };
    float4 psj0, psj1; unsigned pwm;
    auto preload = [&](int tt) {
        int jw = tt * 64 + par * 32;
        psj0 = *(const float4*)(srow + jw + g * 8);
        psj1 = *(const float4*)(srow + jw + g * 8 + 4);
        pwm = mk[tt * 2 + par];
    };

    stage(0, 0);
    preload(0);
    asm volatile("s_waitcnt vmcnt(0)" ::: "memory");
    __builtin_amdgcn_s_barrier();
    __builtin_amdgcn_sched_barrier(0);

    for (int t = 0; t < 32; ++t) {
        int cur = t & 1;
        if (t < 31) stage(t + 1, cur ^ 1);

        // ---- P production: 8 elems for row i, j = t*64 + par*32 + g*8 + e ----
        float sjv[8] = {psj0.x, psj0.y, psj0.z, psj0.w, psj1.x, psj1.y, psj1.z, psj1.w};
        unsigned bb0 = pwm >> (g * 8);
        s16x8 pb;
#pragma unroll
        for (int e = 0; e < 8; ++e) {
            float yL = fmaf(sjv[e], LOG2E, siL);
            float ly = fmaxf(yL, 0.2f * yL);
            float aa = ((bb0 >> e) & 1u) ? (ly - Mlog) : -200.f;  // <= 0 always
            pb[e] = f2bf(__builtin_amdgcn_exp2f(aa));
        }
        *(s16x8*)(Pl + wrP) = pb;

        __builtin_amdgcn_sched_barrier(0);
        asm volatile("s_waitcnt vmcnt(4) lgkmcnt(0)" ::: "memory");  // tile t + P-writes done
        __builtin_amdgcn_s_barrier();
        __builtin_amdgcn_sched_barrier(0);

        // ---- consume: 4 P-frags + 4 A-frags (o-quarter), 16 MFMA (+4 ones for oh==0) ----
        const short* bt = smem + cur * 16384;
        s16x8 pf0 = *(const s16x8*)(Pl + 0 * 1024 + rdP);
        s16x8 pf1 = *(const s16x8*)(Pl + 1 * 1024 + rdP);
        s16x8 pf2 = *(const s16x8*)(Pl + 2 * 1024 + rdP);
        s16x8 pf3 = *(const s16x8*)(Pl + 3 * 1024 + rdP);
        __builtin_amdgcn_s_setprio(1);
#pragma unroll
        for (int f = 0; f < 4; ++f) {
            s16x8 af = *(const s16x8*)(bt + f * 1024 + rdA);
            acc[f][0] = __builtin_amdgcn_mfma_f32_16x16x32_bf16(af, pf0, acc[f][0], 0, 0, 0);
            acc[f][1] = __builtin_amdgcn_mfma_f32_16x16x32_bf16(af, pf1, acc[f][1], 0, 0, 0);
            acc[f][2] = __builtin_amdgcn_mfma_f32_16x16x32_bf16(af, pf2, acc[f][2], 0, 0, 0);
            acc[f][3] = __builtin_amdgcn_mfma_f32_16x16x32_bf16(af, pf3, acc[f][3], 0, 0, 0);
        }
        if (oh == 0) {
            accl[0] = __builtin_amdgcn_mfma_f32_16x16x32_bf16(ones, pf0, accl[0], 0, 0, 0);
            accl[1] = __builtin_amdgcn_mfma_f32_16x16x32_bf16(ones, pf1, accl[1], 0, 0, 0);
            accl[2] = __builtin_amdgcn_mfma_f32_16x16x32_bf16(ones, pf2, accl[2], 0, 0, 0);
            accl[3] = __builtin_amdgcn_mfma_f32_16x16x32_bf16(ones, pf3, accl[3], 0, 0, 0);
        }
        __builtin_amdgcn_s_setprio(0);

        if (t < 31) preload(t + 1);
        __builtin_amdgcn_sched_barrier(0);
        __builtin_amdgcn_s_barrier();   // protect buf[cur] and Pl before next iter's writes
    }

    // ---- epilogue: par-pair partial-sum merge, l broadcast, store bf16 O^T ----
    __syncthreads();
    f32x4* ex = (f32x4*)smem;                 // 64KB: [(oh*16 + f*4 + qf)][lane]
    float* pl    = (float*)Pl;                // l partials (par1, oh0)
    float* plinv = (float*)Pl + 64;           // 1/l broadcast
    if (par) {
#pragma unroll
        for (int f = 0; f < 4; ++f)
#pragma unroll
            for (int qf = 0; qf < 4; ++qf)
                ex[(oh * 16 + f * 4 + qf) * 64 + lane] = acc[f][qf];
        if (oh == 0 && g == 0) {
#pragma unroll
            for (int qf = 0; qf < 4; ++qf) pl[qf * 16 + r16] = accl[qf][0];
        }
    }
    __syncthreads();
    if (!par && oh == 0 && g == 0) {
#pragma unroll
        for (int qf = 0; qf < 4; ++qf) {
            float ls = accl[qf][0] + pl[qf * 16 + r16];
            plinv[qf * 16 + r16] = 1.f / ls;
        }
    }
    __syncthreads();
    if (!par) {
        size_t hbase = (size_t)h * FOUT * M_TOT + gm;
#pragma unroll
        for (int f = 0; f < 4; ++f)
#pragma unroll
            for (int qf = 0; qf < 4; ++qf) {
                f32x4 v = acc[f][qf] + ex[(oh * 16 + f * 4 + qf) * 64 + lane];
                float linv = plinv[qf * 16 + r16];
                int iq = ib + qf * 16 + r16;
#pragma unroll
                for (int rr = 0; rr < 4; ++rr) {
                    int o = oh * 64 + f * 16 + g * 4 + rr;
                    OT[hbase + (size_t)o * M_TOT + iq] = f2bf(v[rr] * linv);
                }
            }
    }
}

// ---------------- head mean + transpose: out[m][o] = 0.25 * sum_h OT[h][o][m] ----------------
__global__ __launch_bounds__(256) void k_reduce(const short* __restrict__ OT, float* __restrict__ out) {
    __shared__ float lds[32][72];
    int mb = blockIdx.x * 64, obt = blockIdx.y * 32;
    int tid = threadIdx.x;
    {
        int o_l = tid >> 3;        // 0..31
        int m_l = (tid & 7) * 8;   // 0..56
        float acc[8] = {};
#pragma unroll
        for (int h = 0; h < H; ++h) {
            s16x8 v = *(const s16x8*)(OT + (size_t)(h * FOUT + obt + o_l) * M_TOT + mb + m_l);
#pragma unroll
            for (int e = 0; e < 8; ++e) acc[e] += bf2f(v[e]);
        }
#pragma unroll
        for (int e = 0; e < 8; ++e) lds[o_l][m_l + e] = acc[e] * 0.25f;
    }
    __syncthreads();
    {
        int m_l = tid >> 2;        // 0..63
        int o_l = (tid & 3) * 8;   // 0,8,16,24
        float4 v0, v1;
        v0.x = lds[o_l + 0][m_l]; v0.y = lds[o_l + 1][m_l];
        v0.z = lds[o_l + 2][m_l]; v0.w = lds[o_l + 3][m_l];
        v1.x = lds[o_l + 4][m_l]; v1.y = lds[o_l + 5][m_l];
        v1.z = lds[o_l + 6][m_l]; v1.w = lds[o_l + 7][m_l];
        float* dst = out + (size_t)(mb + m_l) * FOUT + obt + o_l;
        *(float4*)dst = v0;
        *(float4*)(dst + 4) = v1;
    }
}

extern "C" void kernel_launch(void* const* d_in, const int* in_sizes, int n_in,
                              void* d_out, int out_size, void* d_ws, size_t ws_size,
                              hipStream_t stream) {
    const float* X    = (const float*)d_in[0];  // [B,N,FIN]
    const float* bias = (const float*)d_in[1];  // [B,N,N]
    const float* W    = (const float*)d_in[2];  // [H,FIN,FOUT]
    const float* a    = (const float*)d_in[3];  // [H,FOUT]
    const float* bvec = (const float*)d_in[4];  // [H,FOUT]
    float* out = (float*)d_out;                 // [B,N,FOUT] f32

    // workspace layout (~40 MB high-water)
    char* ws = (char*)d_ws;
    short*    Xbf  = (short*)ws;                               //  4 MB  [8192][256] bf16
    short*    WT   = (short*)(ws + (4u << 20));                // 512 KB [H][256][256] bf16
    float*    q    = (float*)(ws + (4u << 20) + (768u << 10)); //  4 KB
    float*    c    = q + H * FIN;                              // 16 B
    float*    s    = (float*)(ws + (5u << 20));                // 128 KB [H][8192]
    float*    mxp  = (float*)(ws + (5u << 20) + (256u << 10)); // 128 KB [H][8192] row max
    short*    tTs  = (short*)(ws + (6u << 20));                // 16 MB  swizzled tile images
    short*    OT   = (short*)(ws + (22u << 20));               // 16 MB  [H][256][8192] bf16
    unsigned* mask = (unsigned*)(ws + (38u << 20));            //  2 MB  [B][N][N/32] bits

    k_prep<<<321, 256, 0, stream>>>(W, a, bvec, WT, q, c);
    k_s<<<2048, 256, 0, stream>>>(X, q, c, s, Xbf);
    k_maskmax<<<2048, 256, 0, stream>>>(bias, s, mask, mxp);
    k_gemm_t<<<dim3(64, 4, 4), 256, 0, stream>>>(WT, Xbf, bvec, tTs);
    k_attn<<<dim3(32, 4, 4), 512, 73728, stream>>>(tTs, s, mask, mxp, OT);
    k_reduce<<<dim3(128, 8), 256, 0, stream>>>(OT, out);
}

// Round 9
// 114.887 us; speedup vs baseline: 1.3133x; 1.1726x over previous
//
#include <hip/hip_runtime.h>
#include <hip/hip_bf16.h>
#include <stdint.h>

// GAT: B=4, N=2048, F_IN=F_OUT=256, H=4
#define H 4
#define BB 4
#define NN 2048
#define FIN 256
#define FOUT 256
#define M_TOT (BB*NN)   // 8192
#define LOG2E 1.44269504f

typedef float f32x4 __attribute__((ext_vector_type(4)));
typedef short s16x8 __attribute__((ext_vector_type(8)));
typedef unsigned int u32;

static __device__ __forceinline__ short f2bf(float f) {
    return __builtin_bit_cast(short, __float2bfloat16(f));
}
static __device__ __forceinline__ float bf2f(short u) {
    unsigned x = ((unsigned)(unsigned short)u) << 16;
    return __builtin_bit_cast(float, x);
}

// ---------------- prep (fused): W->WT (bf16), q = W.a, c = b.a ----------------
__global__ __launch_bounds__(256) void k_prep(const float* __restrict__ W, const float* __restrict__ a,
                                              const float* __restrict__ bvec,
                                              short* __restrict__ WT, float* __restrict__ q,
                                              float* __restrict__ c) {
    int bid = blockIdx.x;
    if (bid < 64) {
        __shared__ float lds[64][65];
        int h = bid >> 4, kt = (bid >> 2) & 3, ot = bid & 3;
        int kb = kt * 64, ob = ot * 64;
        int tx = threadIdx.x & 63, ty = threadIdx.x >> 6;
#pragma unroll
        for (int r = 0; r < 16; ++r) {
            int k_l = ty + r * 4;
            lds[tx][k_l] = W[(size_t)(h * FIN + kb + k_l) * FOUT + ob + tx];
        }
        __syncthreads();
#pragma unroll
        for (int r = 0; r < 16; ++r) {
            int o_l = ty + r * 4;
            WT[(size_t)(h * FOUT + ob + o_l) * FIN + kb + tx] = f2bf(lds[o_l][tx]);
        }
    } else if (bid < 320) {
        int wv = ((bid - 64) * 256 + threadIdx.x) >> 6;  // 0..1023
        int lane = threadIdx.x & 63;
        int h = wv >> 8, f = wv & 255;
        float4 w4 = *(const float4*)(W + (size_t)(h * FIN + f) * FOUT + lane * 4);
        float4 a4 = *(const float4*)(a + h * FOUT + lane * 4);
        float d = w4.x * a4.x + w4.y * a4.y + w4.z * a4.z + w4.w * a4.w;
#pragma unroll
        for (int off = 32; off; off >>= 1) d += __shfl_xor(d, off);
        if (lane == 0) q[h * FIN + f] = d;
    } else {
        int h = threadIdx.x >> 6, lane = threadIdx.x & 63;
        float4 b4 = *(const float4*)(bvec + h * FOUT + lane * 4);
        float4 a4 = *(const float4*)(a + h * FOUT + lane * 4);
        float d = b4.x * a4.x + b4.y * a4.y + b4.z * a4.z + b4.w * a4.w;
#pragma unroll
        for (int off = 32; off; off >>= 1) d += __shfl_xor(d, off);
        if (lane == 0) c[h] = d;
    }
}

// ---------------- scores (exact fp32) + X->bf16 conversion (fused) ----------------
__global__ __launch_bounds__(256) void k_s(const float* __restrict__ X, const float* __restrict__ q,
                                           const float* __restrict__ c, float* __restrict__ s,
                                           short* __restrict__ Xbf) {
    int m = blockIdx.x * 4 + (threadIdx.x >> 6);
    int lane = threadIdx.x & 63;
    float4 xv = *(const float4*)(X + (size_t)m * FIN + lane * 4);
    short4 xb;
    xb.x = f2bf(xv.x); xb.y = f2bf(xv.y); xb.z = f2bf(xv.z); xb.w = f2bf(xv.w);
    *(short4*)(Xbf + (size_t)m * FIN + lane * 4) = xb;
#pragma unroll
    for (int h = 0; h < H; ++h) {
        float4 qv = *(const float4*)(q + h * FIN + lane * 4);
        float d = xv.x * qv.x + xv.y * qv.y + xv.z * qv.z + xv.w * qv.w;
#pragma unroll
        for (int off = 32; off; off >>= 1) d += __shfl_xor(d, off);
        if (lane == 0) s[h * M_TOT + m] = d + c[h];
    }
}

// ---------------- bias -> mask bits + per-row masked max (s staged in LDS) ----------------
// block = 4 rows (same b). s[4h][2048] for b staged once, XOR-swizzled vs bank conflicts.
__global__ __launch_bounds__(256) void k_maskmax(const float* __restrict__ bias, const float* __restrict__ s,
                                                 unsigned* __restrict__ mask, float* __restrict__ mx) {
    __shared__ float sl[8192];   // 32KB
    int tid = threadIdx.x;
    int row0 = blockIdx.x * 4;
    int b = row0 >> 11;
    // stage s (coalesced); phys = flat ^ (((flat>>5)&7)<<2)
#pragma unroll
    for (int i = 0; i < 8; ++i) {
        int flat = i * 1024 + tid * 4;
        int h = flat >> 11, j = flat & 2047;
        float4 v = *(const float4*)(s + (size_t)h * M_TOT + (size_t)b * NN + j);
        int phys = flat ^ (((flat >> 5) & 7) << 2);
        *(float4*)(sl + phys) = v;
    }
    __syncthreads();

    int w = tid >> 6, lane = tid & 63;
    int row = row0 + w;
    const float* bp = bias + (size_t)row * NN + lane * 32;
    unsigned bits = 0;
#pragma unroll
    for (int k = 0; k < 8; ++k) {
        float4 v = *(const float4*)(bp + k * 4);
        bits |= (v.x > -1.f ? 1u : 0u) << (k * 4 + 0);
        bits |= (v.y > -1.f ? 1u : 0u) << (k * 4 + 1);
        bits |= (v.z > -1.f ? 1u : 0u) << (k * 4 + 2);
        bits |= (v.w > -1.f ? 1u : 0u) << (k * 4 + 3);
    }
    mask[(size_t)row * 64 + lane] = bits;
#pragma unroll
    for (int h = 0; h < H; ++h) {
        float m = -3e38f;
#pragma unroll
        for (int k = 0; k < 8; ++k) {
            int flat = h * 2048 + lane * 32 + k * 4;
            int phys = flat ^ (((flat >> 5) & 7) << 2);
            float4 sv = *(const float4*)(sl + phys);
            m = fmaxf(m, ((bits >> (k * 4 + 0)) & 1u) ? sv.x : -3e38f);
            m = fmaxf(m, ((bits >> (k * 4 + 1)) & 1u) ? sv.y : -3e38f);
            m = fmaxf(m, ((bits >> (k * 4 + 2)) & 1u) ? sv.z : -3e38f);
            m = fmaxf(m, ((bits >> (k * 4 + 3)) & 1u) ? sv.w : -3e38f);
        }
#pragma unroll
        for (int off = 32; off; off >>= 1) m = fmaxf(m, __shfl_xor(m, off));
        if (lane == 0) mx[h * M_TOT + row] = m;
    }
}

// ---------------- tTs = bf16(X@W + b), stored FRAG-MAJOR ----------------
// per (h,b): 32 j-tiles x 32 frags x 1KB. frag = f(o>>4)*2 + par(j-half).
// within frag: lane l holds A[o = f*16 + (l&15)][j = base + (l>>4)*8 + e], 16B.
__global__ __launch_bounds__(256) void k_gemm_t(const short* __restrict__ WT, const short* __restrict__ Xbf,
                                                const float* __restrict__ bvec, short* __restrict__ tTs) {
    __shared__ short ot[64][136];   // bf16 D-tile [64 o][128 m], pad 8
    int h = blockIdx.z;
    int ob = blockIdx.y * 64;
    int mb = blockIdx.x * 128;
    int tid = threadIdx.x;
    int lane = tid & 63, w = tid >> 6;
    int r16 = lane & 15, g = lane >> 4;
    int mw = mb + w * 32;
    f32x4 acc[4][2] = {};
    for (int k = 0; k < FIN; k += 32) {
        s16x8 afr[4], bfr[2];
#pragma unroll
        for (int fa = 0; fa < 4; ++fa)
            afr[fa] = *(const s16x8*)(WT + (size_t)(h * FOUT + ob + fa * 16 + r16) * FIN + k + g * 8);
#pragma unroll
        for (int fb = 0; fb < 2; ++fb)
            bfr[fb] = *(const s16x8*)(Xbf + (size_t)(mw + fb * 16 + r16) * FIN + k + g * 8);
#pragma unroll
        for (int fa = 0; fa < 4; ++fa)
#pragma unroll
            for (int fb = 0; fb < 2; ++fb)
                acc[fa][fb] = __builtin_amdgcn_mfma_f32_16x16x32_bf16(afr[fa], bfr[fb], acc[fa][fb], 0, 0, 0);
    }
#pragma unroll
    for (int fa = 0; fa < 4; ++fa) {
#pragma unroll
        for (int r = 0; r < 4; ++r) {
            int o_l = fa * 16 + g * 4 + r;
            float bv = bvec[h * FOUT + ob + o_l];
#pragma unroll
            for (int fb = 0; fb < 2; ++fb)
                ot[o_l][w * 32 + fb * 16 + r16] = f2bf(acc[fa][fb][r] + bv);
        }
    }
    __syncthreads();
    // frag-major stores: 16 frags (4 f_l x 2 jt_sel x 2 par) x 64 lanes; 4 slots/thread
    int bb = mb >> 11, jloc = mb & 2047;
    int jt0 = jloc >> 6;
    size_t slab = (size_t)((h * 4 + bb) * 32) * 16384;
#pragma unroll
    for (int cc = 0; cc < 4; ++cc) {
        int sid = cc * 256 + tid;       // 0..1023
        int frag = sid >> 6;            // 0..15
        int l = sid & 63;
        int f_l = frag >> 2, jt_sel = (frag >> 1) & 1, par = frag & 1;
        int o_l = f_l * 16 + (l & 15);
        int m_l = jt_sel * 64 + par * 32 + (l >> 4) * 8;
        s16x8 v = *(const s16x8*)&ot[o_l][m_l];
        int fid = ((ob >> 4) + f_l) * 2 + par;
        size_t addr = slab + (size_t)(jt0 + jt_sel) * 16384 + fid * 512 + l * 8;
        *(s16x8*)(tTs + addr) = v;
    }
}

// ---------------- streaming softmax-PV: A-frags from L2 registers, P via LDS ----------------
// 512 threads = 8 waves: par=w&1 (j-half 32), oh=w>>1 (o-quarter 64). q-block 64.
// Per iter: prefetch 4 A-frags (t+1) from L2; produce 8 P-elems -> LDS (2-buf);
// ONE barrier; 4x(1 P-read + 4 MFMA). l = f32 sum of bf16 p (lane-local).
__global__ __launch_bounds__(512, 4) void k_attn(const short* __restrict__ tTs, const float* __restrict__ s,
                                                 const unsigned* __restrict__ mask, const float* __restrict__ mx,
                                                 short* __restrict__ OT) {
    __shared__ short smem[16640];     // P 2x4096 shorts (16KB) | epilogue ex 32KB + pl 512B

    // T1: bijective XCD swizzle (512 blocks)
    int flat = blockIdx.x + 32 * (blockIdx.y + 4 * blockIdx.z);
    int swz = (flat & 7) * 64 + (flat >> 3);
    int qt = swz & 31, b = (swz >> 5) & 3, h = swz >> 7;
    int ib = qt * 64;

    int tid = threadIdx.x;
    int lane = tid & 63, w = tid >> 6;
    int r16 = lane & 15, g = lane >> 4;
    int par = w & 1, oh = w >> 1;        // oh 0..3
    size_t gm = (size_t)b * NN;

    const short* slab = tTs + (size_t)((h * 4 + b) * 32) * 16384;
    const float* srow = s + h * M_TOT + gm;

    // P-production row: i = ib + oh*16 + r16
    int i = ib + oh * 16 + r16;
    float si = srow[i];
    float mxi = mx[h * M_TOT + gm + i];
    float z = si + mxi;
    float Mlog = fmaxf(z, 0.2f * z) * LOG2E;
    float siL = si * LOG2E;
    const unsigned* mk = mask + (gm + i) * 64;

    // P LDS offsets (shorts), XOR swizzle by row&7
    int chk = ((((par << 2) + g) ^ (r16 & 7)) << 3);
    int rdP = r16 * 64 + chk;                 // + qf*1024
    int wrP = oh * 1024 + rdP;

    f32x4 acc[4][4] = {};
    float lsum = 0.f;

    s16x8 acur[4], anext[4];
#pragma unroll
    for (int f = 0; f < 4; ++f)
        acur[f] = *(const s16x8*)(slab + ((oh * 4 + f) * 2 + par) * 512 + lane * 8);

    float4 psj0, psj1; unsigned pwm;
    {
        int jw = par * 32;
        psj0 = *(const float4*)(srow + jw + g * 8);
        psj1 = *(const float4*)(srow + jw + g * 8 + 4);
        pwm = mk[par];
    }

    for (int t = 0; t < 32; ++t) {
        if (t < 31) {
            const short* tp = slab + (size_t)(t + 1) * 16384;
#pragma unroll
            for (int f = 0; f < 4; ++f)
                anext[f] = *(const s16x8*)(tp + ((oh * 4 + f) * 2 + par) * 512 + lane * 8);
        }

        // ---- P production: 8 elems, row i, j = t*64 + par*32 + g*8 + e ----
        float sjv[8] = {psj0.x, psj0.y, psj0.z, psj0.w, psj1.x, psj1.y, psj1.z, psj1.w};
        unsigned bb0 = pwm >> (g * 8);
        s16x8 pb;
#pragma unroll
        for (int e = 0; e < 8; ++e) {
            float yL = fmaf(sjv[e], LOG2E, siL);
            float ly = fmaxf(yL, 0.2f * yL);
            float aa = ((bb0 >> e) & 1u) ? (ly - Mlog) : -200.f;  // <= 0 always
            short pv = f2bf(__builtin_amdgcn_exp2f(aa));
            pb[e] = pv;
            lsum += bf2f(pv);
        }
        *(s16x8*)(smem + (t & 1) * 4096 + wrP) = pb;

        if (t < 31) {
            int jw = (t + 1) * 64 + par * 32;
            psj0 = *(const float4*)(srow + jw + g * 8);
            psj1 = *(const float4*)(srow + jw + g * 8 + 4);
            pwm = mk[(t + 1) * 2 + par];
        }

        asm volatile("s_waitcnt lgkmcnt(0)" ::: "memory");
        __builtin_amdgcn_sched_barrier(0);
        __builtin_amdgcn_s_barrier();
        __builtin_amdgcn_sched_barrier(0);

        // ---- 4 P-frags x 4 A-frags = 16 MFMA ----
        const short* Pb = smem + (t & 1) * 4096;
        __builtin_amdgcn_s_setprio(1);
#pragma unroll
        for (int qf = 0; qf < 4; ++qf) {
            s16x8 pf = *(const s16x8*)(Pb + qf * 1024 + rdP);
            acc[0][qf] = __builtin_amdgcn_mfma_f32_16x16x32_bf16(acur[0], pf, acc[0][qf], 0, 0, 0);
            acc[1][qf] = __builtin_amdgcn_mfma_f32_16x16x32_bf16(acur[1], pf, acc[1][qf], 0, 0, 0);
            acc[2][qf] = __builtin_amdgcn_mfma_f32_16x16x32_bf16(acur[2], pf, acc[2][qf], 0, 0, 0);
            acc[3][qf] = __builtin_amdgcn_mfma_f32_16x16x32_bf16(acur[3], pf, acc[3][qf], 0, 0, 0);
        }
        __builtin_amdgcn_s_setprio(0);

        if (t < 31) {
#pragma unroll
            for (int f = 0; f < 4; ++f) acur[f] = anext[f];
        }
    }

    // ---- epilogue ----
    __syncthreads();
    // l: reduce over g, then over par via LDS; per-row 1/l broadcast
    lsum += __shfl_xor(lsum, 16);
    lsum += __shfl_xor(lsum, 32);
    float* pl    = (float*)(smem + 16384);
    float* plinv = pl + 64;
    if (par == 1 && g == 0) pl[oh * 16 + r16] = lsum;
    __syncthreads();
    if (par == 0 && g == 0) plinv[oh * 16 + r16] = 1.f / (lsum + pl[oh * 16 + r16]);
    __syncthreads();
    float linv[4];
#pragma unroll
    for (int qf = 0; qf < 4; ++qf) linv[qf] = plinv[qf * 16 + r16];

    f32x4* ex = (f32x4*)smem;   // 32KB rounds
    size_t hbase = (size_t)h * FOUT * M_TOT + gm;
#pragma unroll
    for (int rnd = 0; rnd < 2; ++rnd) {
        if (par == 1 && (oh >> 1) == rnd) {
#pragma unroll
            for (int f = 0; f < 4; ++f)
#pragma unroll
                for (int qf = 0; qf < 4; ++qf)
                    ex[(((oh & 1) * 4 + f) * 4 + qf) * 64 + lane] = acc[f][qf];
        }
        __syncthreads();
        if (par == 0 && (oh >> 1) == rnd) {
#pragma unroll
            for (int f = 0; f < 4; ++f)
#pragma unroll
                for (int qf = 0; qf < 4; ++qf) {
                    f32x4 v = acc[f][qf] + ex[(((oh & 1) * 4 + f) * 4 + qf) * 64 + lane];
                    int iq = ib + qf * 16 + r16;
#pragma unroll
                    for (int rr = 0; rr < 4; ++rr) {
                        int o = (oh * 4 + f) * 16 + g * 4 + rr;
                        OT[hbase + (size_t)o * M_TOT + iq] = f2bf(v[rr] * linv[qf]);
                    }
                }
        }
        __syncthreads();
    }
}

// ---------------- head mean + transpose: out[m][o] = 0.25 * sum_h OT[h][o][m] ----------------
__global__ __launch_bounds__(256) void k_reduce(const short* __restrict__ OT, float* __restrict__ out) {
    __shared__ float lds[32][72];
    int mb = blockIdx.x * 64, obt = blockIdx.y * 32;
    int tid = threadIdx.x;
    {
        int o_l = tid >> 3;        // 0..31
        int m_l = (tid & 7) * 8;   // 0..56
        float acc[8] = {};
#pragma unroll
        for (int h = 0; h < H; ++h) {
            s16x8 v = *(const s16x8*)(OT + (size_t)(h * FOUT + obt + o_l) * M_TOT + mb + m_l);
#pragma unroll
            for (int e = 0; e < 8; ++e) acc[e] += bf2f(v[e]);
        }
#pragma unroll
        for (int e = 0; e < 8; ++e) lds[o_l][m_l + e] = acc[e] * 0.25f;
    }
    __syncthreads();
    {
        int m_l = tid >> 2;        // 0..63
        int o_l = (tid & 3) * 8;   // 0,8,16,24
        float4 v0, v1;
        v0.x = lds[o_l + 0][m_l]; v0.y = lds[o_l + 1][m_l];
        v0.z = lds[o_l + 2][m_l]; v0.w = lds[o_l + 3][m_l];
        v1.x = lds[o_l + 4][m_l]; v1.y = lds[o_l + 5][m_l];
        v1.z = lds[o_l + 6][m_l]; v1.w = lds[o_l + 7][m_l];
        float* dst = out + (size_t)(mb + m_l) * FOUT + obt + o_l;
        *(float4*)dst = v0;
        *(float4*)(dst + 4) = v1;
    }
}

extern "C" void kernel_launch(void* const* d_in, const int* in_sizes, int n_in,
                              void* d_out, int out_size, void* d_ws, size_t ws_size,
                              hipStream_t stream) {
    const float* X    = (const float*)d_in[0];  // [B,N,FIN]
    const float* bias = (const float*)d_in[1];  // [B,N,N]
    const float* W    = (const float*)d_in[2];  // [H,FIN,FOUT]
    const float* a    = (const float*)d_in[3];  // [H,FOUT]
    const float* bvec = (const float*)d_in[4];  // [H,FOUT]
    float* out = (float*)d_out;                 // [B,N,FOUT] f32

    // workspace layout (~40 MB high-water)
    char* ws = (char*)d_ws;
    short*    Xbf  = (short*)ws;                               //  4 MB  [8192][256] bf16
    short*    WT   = (short*)(ws + (4u << 20));                // 512 KB [H][256][256] bf16
    float*    q    = (float*)(ws + (4u << 20) + (768u << 10)); //  4 KB
    float*    c    = q + H * FIN;                              // 16 B
    float*    s    = (float*)(ws + (5u << 20));                // 128 KB [H][8192]
    float*    mxp  = (float*)(ws + (5u << 20) + (256u << 10)); // 128 KB [H][8192] row max
    short*    tTs  = (short*)(ws + (6u << 20));                // 16 MB  frag-major tiles
    short*    OT   = (short*)(ws + (22u << 20));               // 16 MB  [H][256][8192] bf16
    unsigned* mask = (unsigned*)(ws + (38u << 20));            //  2 MB  [B][N][N/32] bits

    k_prep<<<321, 256, 0, stream>>>(W, a, bvec, WT, q, c);
    k_s<<<2048, 256, 0, stream>>>(X, q, c, s, Xbf);
    k_maskmax<<<2048, 256, 0, stream>>>(bias, s, mask, mxp);
    k_gemm_t<<<dim3(64, 4, 4), 256, 0, stream>>>(WT, Xbf, bvec, tTs);
    k_attn<<<dim3(32, 4, 4), 512, 0, stream>>>(tTs, s, mask, mxp, OT);
    k_reduce<<<dim3(128, 8), 256, 0, stream>>>(OT, out);
}